// Round 10
// baseline (527.661 us; speedup 1.0000x reference)
//
#include <hip/hip_runtime.h>

#define N_NODES 4096
#define C_CH    128
#define NSPEC   10
#define NCUB    165
#define NQUAD   45
#define NMONO   219   // 165 cubic + 45 quad + 9 linear
#define NBLK    1280  // (s,c) pairs
#define NTILE   8     // node tiles of 512 per (s,c), worst case 4096

// ---- workspace layout (bytes); total ~8.6 MB ----
#define WS_CNT    0            // 10 ints (species counts)
#define WS_LIST   256          // 10*4096 ints = 163840
#define WS_U3SYM  164096       // 4og*165*4k floats = 10560
#define WS_U2SYM  174656       // 4og*45*2k  floats = 1440
#define WS_F      176096       // 4096*128*4 floats  = 8388608

// ---------------------------------------------------------------------------
// Kernel 1 (round-6, proven): blocks 0..7 build permutation-symmetrized
// U3/U2; block 8 buckets nodes by species with LDS counters.
// ---------------------------------------------------------------------------
__global__ __launch_bounds__(256) void k_prep(
        const float* __restrict__ U3_0e, const float* __restrict__ U3_1o,
        const float* __restrict__ U2_0e, const float* __restrict__ U2_1o,
        const int* __restrict__ specie, int* __restrict__ cnt,
        int* __restrict__ list, float* __restrict__ U3sym,
        float* __restrict__ U2sym) {
    int blk = blockIdx.x;
    int t   = threadIdx.x;

    if (blk == 8) {   // ---- lists part (single block, LDS counters) ----
        __shared__ int scnt[NSPEC];
        if (t < NSPEC) scnt[t] = 0;
        __syncthreads();
        for (int i = t; i < N_NODES; i += 256) {
            int s = specie[i];
            int pos = atomicAdd(&scnt[s], 1);
            list[s * N_NODES + pos] = i;
        }
        __syncthreads();
        if (t < NSPEC) cnt[t] = scnt[t];
        return;
    }

    // ---- prep part: blocks 0..7 ----
    __shared__ unsigned char ta[NCUB], tb[NCUB], td[NCUB], qa[NQUAD], qb[NQUAD];
    if (t < NCUB) {
        int idx = 0, a = 0, b = 0, d = 0;
        for (int a0 = 0; a0 < 9; a0++)
            for (int b0 = a0; b0 < 9; b0++)
                for (int d0 = b0; d0 < 9; d0++) {
                    if (idx == t) { a = a0; b = b0; d = d0; }
                    idx++;
                }
        ta[t] = a; tb[t] = b; td[t] = d;
    } else if (t >= NCUB && t < NCUB + NQUAD) {
        int q = t - NCUB, idx = 0, a = 0, b = 0;
        for (int a0 = 0; a0 < 9; a0++)
            for (int b0 = a0; b0 < 9; b0++) { if (idx == q) { a = a0; b = b0; } idx++; }
        qa[q] = a; qb[q] = b;
    }
    __syncthreads();

    for (int task = blk * 256 + t; task < 2640 + 360; task += 8 * 256) {
        if (task < 2640) {               // cubic: og(4) * m(165) * k(4)
            int og = task / 660;
            int r  = task - og * 660;
            int m  = r >> 2, k = r & 3;
            int a = ta[m], b = tb[m], d = td[m];
            const float* U3 = (og == 0) ? U3_0e : U3_1o;
            int o = (og == 0) ? 0 : og - 1;
            const float* Ub = U3 + (size_t)o * 2916;   // [p][q][i][k] 324/36/4/1
            #define U3AT(p,q,i) Ub[((p)*9+(q))*36 + (i)*4 + k]
            float sum = U3AT(a,b,d) + U3AT(a,d,b) + U3AT(b,a,d)
                      + U3AT(b,d,a) + U3AT(d,a,b) + U3AT(d,b,a);
            #undef U3AT
            float sc = (a == b && b == d) ? (1.f/6.f)
                     : ((a == b || b == d || a == d) ? 0.5f : 1.f);
            U3sym[(og * 165 + m) * 4 + k] = sum * sc;
        } else {                          // quad: og(4) * q(45) * k(2)
            int t2 = task - 2640;
            int og = t2 / 90;
            int r  = t2 - og * 90;
            int q  = r >> 1, k = r & 1;
            int a = qa[q], b = qb[q];
            const float* U2 = (og == 0) ? U2_0e : U2_1o;
            int o = (og == 0) ? 0 : og - 1;
            const float* Ub = U2 + (size_t)o * 162;    // [p][i][k] 18/2/1
            float sum = Ub[(a*9 + b)*2 + k] + Ub[(b*9 + a)*2 + k];
            if (a == b) sum *= 0.5f;
            U2sym[(og * 45 + q) * 2 + k] = sum;
        }
    }
}

// ---------------------------------------------------------------------------
// Kernel 2: coeff-fused main contraction -- FULL UNROLL, x in REGISTERS.
// All (a,b,d) indices compile-time -> zero per-monomial address math, zero
// x ds_reads. Only DS traffic: 219 wave-uniform broadcast ds_read_b128 coeff
// loads at immediate offsets from one base. The R3/R4 spill (scheduler
// clustering all loads -> 256 VGPR + scratch) is blocked by
// sched_group_barrier {DS_READ:1, VALU:8} after every monomial group (T19:
// the ONLY schedule-control primitive verified in .s to bind on gfx950).
// 2 nodes/thread, 256 threads, round-0 scattered x global reads (high MLP).
// LDS = cfs only (3.5KB) -> 8 blocks/CU. Per-node FP order identical to
// rounds 5-9 (bitwise-identical f).
// ---------------------------------------------------------------------------
__global__ __launch_bounds__(256) void k_main(const float* __restrict__ x,
        const int* __restrict__ cnt, const int* __restrict__ list,
        const float* __restrict__ U3sym, const float* __restrict__ U2sym,
        const float* __restrict__ U1_0e, const float* __restrict__ U1_1o,
        const float* __restrict__ W3_0e, const float* __restrict__ W3_1o,
        const float* __restrict__ W2_0e, const float* __restrict__ W2_1o,
        const float* __restrict__ W1_0e, const float* __restrict__ W1_1o,
        float* __restrict__ fout) {
    __shared__ float4 cfs4[NMONO];           // 3504 B
    int bx   = blockIdx.x;
    int tile = bx / NBLK;
    int blk  = bx - tile * NBLK;
    int s = blk >> 7, c = blk & 127;
    int n = cnt[s];
    if (tile * 512 >= n) return;             // block-uniform exit (before sync)

    int tid = threadIdx.x;

    // ---- coefficient preamble (fused k_coeff, unchanged math) ----
    float* cfs = (float*)cfs4;
    for (int e = tid; e < NMONO * 4; e += 256) {
        int m = e >> 2, og = e & 3;
        float val;
        if (m < NCUB) {
            const float* W3 = (og == 0) ? W3_0e : W3_1o;   // [s][k][c] 512/128/1
            const float* u  = U3sym + (og * 165 + m) * 4;
            val = u[0] * W3[s*512 +       c] + u[1] * W3[s*512 + 128 + c]
                + u[2] * W3[s*512 + 256 + c] + u[3] * W3[s*512 + 384 + c];
        } else if (m < NCUB + NQUAD) {
            int q = m - NCUB;
            const float* W2 = (og == 0) ? W2_0e : W2_1o;   // [s][k][c] 256/128/1
            const float* u  = U2sym + (og * 45 + q) * 2;
            val = u[0] * W2[s*256 + c] + u[1] * W2[s*256 + 128 + c];
        } else {
            int l = m - (NCUB + NQUAD);
            const float* U1 = (og == 0) ? U1_0e : U1_1o;   // [o][i][k=1]
            const float* W1 = (og == 0) ? W1_0e : W1_1o;   // [s][1][c]
            int o = (og == 0) ? 0 : og - 1;
            val = U1[o * 9 + l] * W1[s * 128 + c];
        }
        cfs[e] = val;
    }
    __syncthreads();

    // ---- x into registers (round-0 scattered pattern, high MLP) ----
    const int* __restrict__ lst = list + s * N_NODES;
    int i0 = tile * 512 + tid;
    int i1 = i0 + 256;
    int b0 = lst[i0 < n ? i0 : 0];
    int b1 = lst[i1 < n ? i1 : 0];
    const float* xp0 = x + ((size_t)b0 * C_CH + c) * 9;
    const float* xp1 = x + ((size_t)b1 * C_CH + c) * 9;
    float x0[9], x1[9];
    #pragma unroll
    for (int i = 0; i < 9; i++) { x0[i] = xp0[i]; x1[i] = xp1[i]; }

    float4 a0 = make_float4(0.f, 0.f, 0.f, 0.f);
    float4 a1 = make_float4(0.f, 0.f, 0.f, 0.f);
    int m3 = 0, m2 = 0;

    #define FMA4(acc, cf, xv) \
        acc.x = fmaf(cf.x, xv, acc.x); acc.y = fmaf(cf.y, xv, acc.y); \
        acc.z = fmaf(cf.z, xv, acc.z); acc.w = fmaf(cf.w, xv, acc.w);
    // pace the scheduler: 1 DS_READ then ~8 VALU, repeating (T19).
    #define PACE() \
        __builtin_amdgcn_sched_group_barrier(0x100, 1, 0); \
        __builtin_amdgcn_sched_group_barrier(0x002, 8, 0);

    #pragma unroll
    for (int a = 0; a < 9; a++) {
        {   // linear term
            float4 cl = cfs4[210 + a];
            FMA4(a0, cl, x0[a])  FMA4(a1, cl, x1[a])
            PACE()
        }
        #pragma unroll
        for (int b = a; b < 9; b++) {
            float p0 = x0[a] * x0[b], p1 = x1[a] * x1[b];
            {
                float4 cq = cfs4[165 + m2]; m2++;
                FMA4(a0, cq, p0)  FMA4(a1, cq, p1)
                PACE()
            }
            #pragma unroll
            for (int d = b; d < 9; d++) {
                float4 c3 = cfs4[m3]; m3++;
                float q0 = p0 * x0[d], q1 = p1 * x1[d];
                FMA4(a0, c3, q0)  FMA4(a1, c3, q1)
                PACE()
            }
        }
    }
    #undef PACE
    #undef FMA4

    if (i0 < n) *(float4*)&fout[((size_t)b0 * C_CH + c) * 4] = a0;
    if (i1 < n) *(float4*)&fout[((size_t)b1 * C_CH + c) * 4] = a1;
}

// ---------------------------------------------------------------------------
// Kernel 3: epilogue linear (round-0/5/6 version, unchanged).
// ---------------------------------------------------------------------------
__global__ __launch_bounds__(256) void k_epi(const float* __restrict__ f,
        const float* __restrict__ W0, const float* __restrict__ W1,
        const float* __restrict__ bias, float* __restrict__ out) {
    __shared__ float smem[128 * 65];        // ftile [c][n(64)+pad]; reused as trbuf [j][n]
    int bx = blockIdx.x;
    int ntile = bx >> 3, jg = bx & 7;       // 64 n-tiles x 8 j-groups of 64
    int n0 = ntile * 64;
    int t  = threadIdx.x;
    int o  = jg >> 1;                        // output component 0..3 (uniform per block)

    #pragma unroll
    for (int r = 0; r < 32; ++r) {
        int flat = r * 256 + t;              // 8192 = 64n * 128c
        int n = flat >> 7, c = flat & 127;
        smem[c * 65 + n] = f[(size_t)(n0 + n) * 512 + c * 4 + o];
    }
    __syncthreads();

    int w    = __builtin_amdgcn_readfirstlane((int)(t >> 6));
    int lane = t & 63;
    int mb   = (jg & 1) * 64 + w * 16;       // wave's m base (uniform)
    const float* __restrict__ Wsel = (o == 0) ? W0 : W1;

    float acc[16];
    #pragma unroll
    for (int jj = 0; jj < 16; jj++) acc[jj] = 0.f;

    #pragma unroll 4
    for (int c = 0; c < 128; ++c) {
        float fv = smem[c * 65 + lane];
        #pragma unroll
        for (int jj = 0; jj < 16; jj++)
            acc[jj] = fmaf(fv, Wsel[c * 128 + mb + jj], acc[jj]);
    }
    __syncthreads();                          // all waves done reading ftile

    const float scale = 0.08838834764831845f; // 1/sqrt(128)
    #pragma unroll
    for (int jj = 0; jj < 16; jj++) {
        float v = acc[jj] * scale;
        if (o == 0) v += bias[mb + jj];
        smem[(w * 16 + jj) * 65 + lane] = v;  // trbuf[j_local][n]
    }
    __syncthreads();

    #pragma unroll
    for (int r = 0; r < 16; ++r) {
        int flat = r * 256 + t;               // 4096 = 64j * 64n
        int jl = flat & 63, n = flat >> 6;
        int m  = (jg & 1) * 64 + jl;
        int col = (o == 0) ? m : (128 + m * 3 + (o - 1));
        out[(size_t)(n0 + n) * 512 + col] = smem[jl * 65 + n];
    }
}

extern "C" void kernel_launch(void* const* d_in, const int* in_sizes, int n_in,
                              void* d_out, int out_size, void* d_ws, size_t ws_size,
                              hipStream_t stream) {
    const float* x     = (const float*)d_in[0];
    const int*   spec  = (const int*)  d_in[1];
    const float* U3_0e = (const float*)d_in[2];
    const float* U2_0e = (const float*)d_in[3];
    const float* U1_0e = (const float*)d_in[4];
    const float* W3_0e = (const float*)d_in[5];
    const float* W2_0e = (const float*)d_in[6];
    const float* W1_0e = (const float*)d_in[7];
    const float* U3_1o = (const float*)d_in[8];
    const float* U2_1o = (const float*)d_in[9];
    const float* U1_1o = (const float*)d_in[10];
    const float* W3_1o = (const float*)d_in[11];
    const float* W2_1o = (const float*)d_in[12];
    const float* W1_1o = (const float*)d_in[13];
    const float* Wlin0 = (const float*)d_in[14];
    const float* Wlin1 = (const float*)d_in[15];
    const float* bias0 = (const float*)d_in[16];
    float* out = (float*)d_out;

    char* ws = (char*)d_ws;
    int*   cnt   = (int*)  (ws + WS_CNT);
    int*   list  = (int*)  (ws + WS_LIST);
    float* U3sym = (float*)(ws + WS_U3SYM);
    float* U2sym = (float*)(ws + WS_U2SYM);
    float* f     = (float*)(ws + WS_F);
    (void)in_sizes; (void)n_in; (void)out_size; (void)ws_size;

    // K1: blocks 0..7 = symmetrize U3/U2; block 8 = species bucketing.
    hipLaunchKernelGGL(k_prep, dim3(9), dim3(256), 0, stream,
                       U3_0e, U3_1o, U2_0e, U2_1o, spec, cnt, list, U3sym, U2sym);
    // K2: coeff-fused contraction, full unroll + SGB pacing. Dead tiles exit.
    hipLaunchKernelGGL(k_main, dim3(NBLK * NTILE), dim3(256), 0, stream,
                       x, cnt, list, U3sym, U2sym, U1_0e, U1_1o,
                       W3_0e, W3_1o, W2_0e, W2_1o, W1_0e, W1_1o, f);
    // K3: epilogue linear.
    hipLaunchKernelGGL(k_epi, dim3(512), dim3(256), 0, stream,
                       f, Wlin0, Wlin1, bias0, out);
}

// Round 11
// 164.298 us; speedup vs baseline: 3.2116x; 3.2116x over previous
//
#include <hip/hip_runtime.h>

#define N_NODES 4096
#define C_CH    128
#define NSPEC   10
#define NCUB    165
#define NQUAD   45
#define NMONO   219   // 165 cubic + 45 quad + 9 linear
#define NBLK    1280  // (s,c) pairs

// ---- workspace layout (bytes); total ~8.6 MB ----
#define WS_CNT    0            // 10 ints (species counts)
#define WS_LIST   256          // 10*4096 ints = 163840
#define WS_U3SYM  164096       // 4og*165*4k floats = 10560
#define WS_U2SYM  174656       // 4og*45*2k  floats = 1440
#define WS_F      176096       // 4096*128*4 floats  = 8388608

// ---------------------------------------------------------------------------
// Kernel 1 (round-6, proven): blocks 0..7 build permutation-symmetrized
// U3/U2; block 8 buckets nodes by species with LDS counters.
// ---------------------------------------------------------------------------
__global__ __launch_bounds__(256) void k_prep(
        const float* __restrict__ U3_0e, const float* __restrict__ U3_1o,
        const float* __restrict__ U2_0e, const float* __restrict__ U2_1o,
        const int* __restrict__ specie, int* __restrict__ cnt,
        int* __restrict__ list, float* __restrict__ U3sym,
        float* __restrict__ U2sym) {
    int blk = blockIdx.x;
    int t   = threadIdx.x;

    if (blk == 8) {   // ---- lists part (single block, LDS counters) ----
        __shared__ int scnt[NSPEC];
        if (t < NSPEC) scnt[t] = 0;
        __syncthreads();
        for (int i = t; i < N_NODES; i += 256) {
            int s = specie[i];
            int pos = atomicAdd(&scnt[s], 1);
            list[s * N_NODES + pos] = i;
        }
        __syncthreads();
        if (t < NSPEC) cnt[t] = scnt[t];
        return;
    }

    // ---- prep part: blocks 0..7 ----
    __shared__ unsigned char ta[NCUB], tb[NCUB], td[NCUB], qa[NQUAD], qb[NQUAD];
    if (t < NCUB) {
        int idx = 0, a = 0, b = 0, d = 0;
        for (int a0 = 0; a0 < 9; a0++)
            for (int b0 = a0; b0 < 9; b0++)
                for (int d0 = b0; d0 < 9; d0++) {
                    if (idx == t) { a = a0; b = b0; d = d0; }
                    idx++;
                }
        ta[t] = a; tb[t] = b; td[t] = d;
    } else if (t >= NCUB && t < NCUB + NQUAD) {
        int q = t - NCUB, idx = 0, a = 0, b = 0;
        for (int a0 = 0; a0 < 9; a0++)
            for (int b0 = a0; b0 < 9; b0++) { if (idx == q) { a = a0; b = b0; } idx++; }
        qa[q] = a; qb[q] = b;
    }
    __syncthreads();

    for (int task = blk * 256 + t; task < 2640 + 360; task += 8 * 256) {
        if (task < 2640) {               // cubic: og(4) * m(165) * k(4)
            int og = task / 660;
            int r  = task - og * 660;
            int m  = r >> 2, k = r & 3;
            int a = ta[m], b = tb[m], d = td[m];
            const float* U3 = (og == 0) ? U3_0e : U3_1o;
            int o = (og == 0) ? 0 : og - 1;
            const float* Ub = U3 + (size_t)o * 2916;   // [p][q][i][k] 324/36/4/1
            #define U3AT(p,q,i) Ub[((p)*9+(q))*36 + (i)*4 + k]
            float sum = U3AT(a,b,d) + U3AT(a,d,b) + U3AT(b,a,d)
                      + U3AT(b,d,a) + U3AT(d,a,b) + U3AT(d,b,a);
            #undef U3AT
            float sc = (a == b && b == d) ? (1.f/6.f)
                     : ((a == b || b == d || a == d) ? 0.5f : 1.f);
            U3sym[(og * 165 + m) * 4 + k] = sum * sc;
        } else {                          // quad: og(4) * q(45) * k(2)
            int t2 = task - 2640;
            int og = t2 / 90;
            int r  = t2 - og * 90;
            int q  = r >> 1, k = r & 1;
            int a = qa[q], b = qb[q];
            const float* U2 = (og == 0) ? U2_0e : U2_1o;
            int o = (og == 0) ? 0 : og - 1;
            const float* Ub = U2 + (size_t)o * 162;    // [p][i][k] 18/2/1
            float sum = Ub[(a*9 + b)*2 + k] + Ub[(b*9 + a)*2 + k];
            if (a == b) sum *= 0.5f;
            U2sym[(og * 45 + q) * 2 + k] = sum;
        }
    }
}

// ---------------------------------------------------------------------------
// Kernel 2: coeff-fused main contraction -- ROUND-6 BODY (proven best:
// ~43us, VGPR 36, zero scratch). 256 threads, 2 nodes/thread, x in LDS
// float2[i][tid], rolled loops (#pragma unroll 1) -- the only structure of
// six tried that neither spills nor starves. Coefficients staged once to
// LDS, read as wave-uniform broadcast ds_read_b128 with loop-carried
// offsets (unhoistable, unpromotable).
// DELTA vs round 6: grid = exactly NBLK with an internal tile loop (round-9
// pattern, spill-safe with rolled bodies) instead of NBLK*8 with ~8960
// dead-block exits -- trims dispatch drain.
// STANDING CONSTRAINT (R2/R3/R4/R10): full unroll of the 219-monomial body
// spills at 256 VGPR regardless of sched_barrier/sched_group_barrier; the
// unroll axis is closed on this compiler.
// ---------------------------------------------------------------------------
__global__ __launch_bounds__(256) void k_main(const float* __restrict__ x,
        const int* __restrict__ cnt, const int* __restrict__ list,
        const float* __restrict__ U3sym, const float* __restrict__ U2sym,
        const float* __restrict__ U1_0e, const float* __restrict__ U1_1o,
        const float* __restrict__ W3_0e, const float* __restrict__ W3_1o,
        const float* __restrict__ W2_0e, const float* __restrict__ W2_1o,
        const float* __restrict__ W1_0e, const float* __restrict__ W1_1o,
        float* __restrict__ fout) {
    __shared__ float  cfs[NMONO * 4];        // 3504 B
    __shared__ float2 xsh[9 * 256];          // 18432 B, [i][tid]
    int blk = blockIdx.x;                    // s*128 + c
    int s = blk >> 7, c = blk & 127;
    int n = cnt[s];
    if (n == 0) return;                      // block-uniform exit (before sync)

    int tid = threadIdx.x;

    // ---- coefficient preamble (fused k_coeff, unchanged math) ----
    for (int e = tid; e < NMONO * 4; e += 256) {
        int m = e >> 2, og = e & 3;
        float val;
        if (m < NCUB) {
            const float* W3 = (og == 0) ? W3_0e : W3_1o;   // [s][k][c] 512/128/1
            const float* u  = U3sym + (og * 165 + m) * 4;
            val = u[0] * W3[s*512 +       c] + u[1] * W3[s*512 + 128 + c]
                + u[2] * W3[s*512 + 256 + c] + u[3] * W3[s*512 + 384 + c];
        } else if (m < NCUB + NQUAD) {
            int q = m - NCUB;
            const float* W2 = (og == 0) ? W2_0e : W2_1o;   // [s][k][c] 256/128/1
            const float* u  = U2sym + (og * 45 + q) * 2;
            val = u[0] * W2[s*256 + c] + u[1] * W2[s*256 + 128 + c];
        } else {
            int l = m - (NCUB + NQUAD);
            const float* U1 = (og == 0) ? U1_0e : U1_1o;   // [o][i][k=1]
            const float* W1 = (og == 0) ? W1_0e : W1_1o;   // [s][1][c]
            int o = (og == 0) ? 0 : og - 1;
            val = U1[o * 9 + l] * W1[s * 128 + c];
        }
        cfs[e] = val;
    }

    const int* __restrict__ lst = list + s * N_NODES;

    for (int base = 0; base < n; base += 512) {
        __syncthreads();                     // cfs ready / prior tile's xsh reads done
        int i0 = base + tid;
        int i1 = i0 + 256;
        int b0 = lst[i0 < n ? i0 : 0];
        int b1 = lst[i1 < n ? i1 : 0];
        const float* xp0 = x + ((size_t)b0 * C_CH + c) * 9;
        const float* xp1 = x + ((size_t)b1 * C_CH + c) * 9;
        #pragma unroll
        for (int i = 0; i < 9; i++)
            xsh[i * 256 + tid] = make_float2(xp0[i], xp1[i]);
        __syncthreads();

        float a0[4] = {0.f, 0.f, 0.f, 0.f};
        float a1[4] = {0.f, 0.f, 0.f, 0.f};
        int mcub = 0, mquad = 0;

        #pragma unroll 1
        for (int a = 0; a < 9; a++) {
            float2 xa = xsh[a * 256 + tid];
            {   // linear term
                float4 cl = *(const float4*)&cfs[(210 + a) * 4];
                a0[0] = fmaf(cl.x, xa.x, a0[0]);  a1[0] = fmaf(cl.x, xa.y, a1[0]);
                a0[1] = fmaf(cl.y, xa.x, a0[1]);  a1[1] = fmaf(cl.y, xa.y, a1[1]);
                a0[2] = fmaf(cl.z, xa.x, a0[2]);  a1[2] = fmaf(cl.z, xa.y, a1[2]);
                a0[3] = fmaf(cl.w, xa.x, a0[3]);  a1[3] = fmaf(cl.w, xa.y, a1[3]);
            }
            #pragma unroll 1
            for (int b = a; b < 9; b++) {
                float2 xb = xsh[b * 256 + tid];
                float p0 = xa.x * xb.x, p1 = xa.y * xb.y;
                {
                    float4 cq = *(const float4*)&cfs[(165 + mquad) * 4]; mquad++;
                    a0[0] = fmaf(cq.x, p0, a0[0]);  a1[0] = fmaf(cq.x, p1, a1[0]);
                    a0[1] = fmaf(cq.y, p0, a0[1]);  a1[1] = fmaf(cq.y, p1, a1[1]);
                    a0[2] = fmaf(cq.z, p0, a0[2]);  a1[2] = fmaf(cq.z, p1, a1[2]);
                    a0[3] = fmaf(cq.w, p0, a0[3]);  a1[3] = fmaf(cq.w, p1, a1[3]);
                }
                #pragma unroll 1
                for (int d = b; d < 9; d++) {
                    float2 xd = xsh[d * 256 + tid];
                    float4 c3 = *(const float4*)&cfs[mcub * 4]; mcub++;
                    float q0 = p0 * xd.x, q1 = p1 * xd.y;
                    a0[0] = fmaf(c3.x, q0, a0[0]);  a1[0] = fmaf(c3.x, q1, a1[0]);
                    a0[1] = fmaf(c3.y, q0, a0[1]);  a1[1] = fmaf(c3.y, q1, a1[1]);
                    a0[2] = fmaf(c3.z, q0, a0[2]);  a1[2] = fmaf(c3.z, q1, a1[2]);
                    a0[3] = fmaf(c3.w, q0, a0[3]);  a1[3] = fmaf(c3.w, q1, a1[3]);
                }
            }
        }
        if (i0 < n) *(float4*)&fout[((size_t)b0 * C_CH + c) * 4] = make_float4(a0[0], a0[1], a0[2], a0[3]);
        if (i1 < n) *(float4*)&fout[((size_t)b1 * C_CH + c) * 4] = make_float4(a1[0], a1[1], a1[2], a1[3]);
    }
}

// ---------------------------------------------------------------------------
// Kernel 3: epilogue linear (round-0/5/6 version, unchanged).
// ---------------------------------------------------------------------------
__global__ __launch_bounds__(256) void k_epi(const float* __restrict__ f,
        const float* __restrict__ W0, const float* __restrict__ W1,
        const float* __restrict__ bias, float* __restrict__ out) {
    __shared__ float smem[128 * 65];        // ftile [c][n(64)+pad]; reused as trbuf [j][n]
    int bx = blockIdx.x;
    int ntile = bx >> 3, jg = bx & 7;       // 64 n-tiles x 8 j-groups of 64
    int n0 = ntile * 64;
    int t  = threadIdx.x;
    int o  = jg >> 1;                        // output component 0..3 (uniform per block)

    #pragma unroll
    for (int r = 0; r < 32; ++r) {
        int flat = r * 256 + t;              // 8192 = 64n * 128c
        int n = flat >> 7, c = flat & 127;
        smem[c * 65 + n] = f[(size_t)(n0 + n) * 512 + c * 4 + o];
    }
    __syncthreads();

    int w    = __builtin_amdgcn_readfirstlane((int)(t >> 6));
    int lane = t & 63;
    int mb   = (jg & 1) * 64 + w * 16;       // wave's m base (uniform)
    const float* __restrict__ Wsel = (o == 0) ? W0 : W1;

    float acc[16];
    #pragma unroll
    for (int jj = 0; jj < 16; jj++) acc[jj] = 0.f;

    #pragma unroll 4
    for (int c = 0; c < 128; ++c) {
        float fv = smem[c * 65 + lane];
        #pragma unroll
        for (int jj = 0; jj < 16; jj++)
            acc[jj] = fmaf(fv, Wsel[c * 128 + mb + jj], acc[jj]);
    }
    __syncthreads();                          // all waves done reading ftile

    const float scale = 0.08838834764831845f; // 1/sqrt(128)
    #pragma unroll
    for (int jj = 0; jj < 16; jj++) {
        float v = acc[jj] * scale;
        if (o == 0) v += bias[mb + jj];
        smem[(w * 16 + jj) * 65 + lane] = v;  // trbuf[j_local][n]
    }
    __syncthreads();

    #pragma unroll
    for (int r = 0; r < 16; ++r) {
        int flat = r * 256 + t;               // 4096 = 64j * 64n
        int jl = flat & 63, n = flat >> 6;
        int m  = (jg & 1) * 64 + jl;
        int col = (o == 0) ? m : (128 + m * 3 + (o - 1));
        out[(size_t)(n0 + n) * 512 + col] = smem[jl * 65 + n];
    }
}

extern "C" void kernel_launch(void* const* d_in, const int* in_sizes, int n_in,
                              void* d_out, int out_size, void* d_ws, size_t ws_size,
                              hipStream_t stream) {
    const float* x     = (const float*)d_in[0];
    const int*   spec  = (const int*)  d_in[1];
    const float* U3_0e = (const float*)d_in[2];
    const float* U2_0e = (const float*)d_in[3];
    const float* U1_0e = (const float*)d_in[4];
    const float* W3_0e = (const float*)d_in[5];
    const float* W2_0e = (const float*)d_in[6];
    const float* W1_0e = (const float*)d_in[7];
    const float* U3_1o = (const float*)d_in[8];
    const float* U2_1o = (const float*)d_in[9];
    const float* U1_1o = (const float*)d_in[10];
    const float* W3_1o = (const float*)d_in[11];
    const float* W2_1o = (const float*)d_in[12];
    const float* W1_1o = (const float*)d_in[13];
    const float* Wlin0 = (const float*)d_in[14];
    const float* Wlin1 = (const float*)d_in[15];
    const float* bias0 = (const float*)d_in[16];
    float* out = (float*)d_out;

    char* ws = (char*)d_ws;
    int*   cnt   = (int*)  (ws + WS_CNT);
    int*   list  = (int*)  (ws + WS_LIST);
    float* U3sym = (float*)(ws + WS_U3SYM);
    float* U2sym = (float*)(ws + WS_U2SYM);
    float* f     = (float*)(ws + WS_F);
    (void)in_sizes; (void)n_in; (void)out_size; (void)ws_size;

    // K1: blocks 0..7 = symmetrize U3/U2; block 8 = species bucketing.
    hipLaunchKernelGGL(k_prep, dim3(9), dim3(256), 0, stream,
                       U3_0e, U3_1o, U2_0e, U2_1o, spec, cnt, list, U3sym, U2sym);
    // K2: coeff-fused contraction. Exactly NBLK blocks; tile loop inside.
    hipLaunchKernelGGL(k_main, dim3(NBLK), dim3(256), 0, stream,
                       x, cnt, list, U3sym, U2sym, U1_0e, U1_1o,
                       W3_0e, W3_1o, W2_0e, W2_1o, W1_0e, W1_1o, f);
    // K3: epilogue linear.
    hipLaunchKernelGGL(k_epi, dim3(512), dim3(256), 0, stream,
                       f, Wlin0, Wlin1, bias0, out);
}

// Round 12
// 162.077 us; speedup vs baseline: 3.2556x; 1.0137x over previous
//
#include <hip/hip_runtime.h>

#define N_NODES 4096
#define C_CH    128
#define NSPEC   10
#define NCUB    165
#define NQUAD   45
#define NMONO   219   // 165 cubic + 45 quad + 9 linear
#define NBLK    1280  // (s,c) pairs

// ---- workspace layout (bytes); total ~8.6 MB ----
#define WS_CNT    0            // 10 ints (species counts)
#define WS_LIST   256          // 10*4096 ints = 163840
#define WS_U3SYM  164096       // 4og*165*4k floats = 10560
#define WS_U2SYM  174656       // 4og*45*2k  floats = 1440
#define WS_F      176096       // 4096*128*4 floats  = 8388608

// ---------------------------------------------------------------------------
// Kernel 1 (round-6, proven): blocks 0..7 build permutation-symmetrized
// U3/U2; block 8 buckets nodes by species with LDS counters.
// ---------------------------------------------------------------------------
__global__ __launch_bounds__(256) void k_prep(
        const float* __restrict__ U3_0e, const float* __restrict__ U3_1o,
        const float* __restrict__ U2_0e, const float* __restrict__ U2_1o,
        const int* __restrict__ specie, int* __restrict__ cnt,
        int* __restrict__ list, float* __restrict__ U3sym,
        float* __restrict__ U2sym) {
    int blk = blockIdx.x;
    int t   = threadIdx.x;

    if (blk == 8) {   // ---- lists part (single block, LDS counters) ----
        __shared__ int scnt[NSPEC];
        if (t < NSPEC) scnt[t] = 0;
        __syncthreads();
        for (int i = t; i < N_NODES; i += 256) {
            int s = specie[i];
            int pos = atomicAdd(&scnt[s], 1);
            list[s * N_NODES + pos] = i;
        }
        __syncthreads();
        if (t < NSPEC) cnt[t] = scnt[t];
        return;
    }

    // ---- prep part: blocks 0..7 ----
    __shared__ unsigned char ta[NCUB], tb[NCUB], td[NCUB], qa[NQUAD], qb[NQUAD];
    if (t < NCUB) {
        int idx = 0, a = 0, b = 0, d = 0;
        for (int a0 = 0; a0 < 9; a0++)
            for (int b0 = a0; b0 < 9; b0++)
                for (int d0 = b0; d0 < 9; d0++) {
                    if (idx == t) { a = a0; b = b0; d = d0; }
                    idx++;
                }
        ta[t] = a; tb[t] = b; td[t] = d;
    } else if (t >= NCUB && t < NCUB + NQUAD) {
        int q = t - NCUB, idx = 0, a = 0, b = 0;
        for (int a0 = 0; a0 < 9; a0++)
            for (int b0 = a0; b0 < 9; b0++) { if (idx == q) { a = a0; b = b0; } idx++; }
        qa[q] = a; qb[q] = b;
    }
    __syncthreads();

    for (int task = blk * 256 + t; task < 2640 + 360; task += 8 * 256) {
        if (task < 2640) {               // cubic: og(4) * m(165) * k(4)
            int og = task / 660;
            int r  = task - og * 660;
            int m  = r >> 2, k = r & 3;
            int a = ta[m], b = tb[m], d = td[m];
            const float* U3 = (og == 0) ? U3_0e : U3_1o;
            int o = (og == 0) ? 0 : og - 1;
            const float* Ub = U3 + (size_t)o * 2916;   // [p][q][i][k] 324/36/4/1
            #define U3AT(p,q,i) Ub[((p)*9+(q))*36 + (i)*4 + k]
            float sum = U3AT(a,b,d) + U3AT(a,d,b) + U3AT(b,a,d)
                      + U3AT(b,d,a) + U3AT(d,a,b) + U3AT(d,b,a);
            #undef U3AT
            float sc = (a == b && b == d) ? (1.f/6.f)
                     : ((a == b || b == d || a == d) ? 0.5f : 1.f);
            U3sym[(og * 165 + m) * 4 + k] = sum * sc;
        } else {                          // quad: og(4) * q(45) * k(2)
            int t2 = task - 2640;
            int og = t2 / 90;
            int r  = t2 - og * 90;
            int q  = r >> 1, k = r & 1;
            int a = qa[q], b = qb[q];
            const float* U2 = (og == 0) ? U2_0e : U2_1o;
            int o = (og == 0) ? 0 : og - 1;
            const float* Ub = U2 + (size_t)o * 162;    // [p][i][k] 18/2/1
            float sum = Ub[(a*9 + b)*2 + k] + Ub[(b*9 + a)*2 + k];
            if (a == b) sum *= 0.5f;
            U2sym[(og * 45 + q) * 2 + k] = sum;
        }
    }
}

// ---------------------------------------------------------------------------
// Kernel 2: coeff-fused main contraction -- round-6/11 rolled body with the
// d-loop MANUALLY UNROLLED x3: batches {3x ds_read_b64 + 3x ds_read_b128}
// per lgkmcnt wait (was 1+1), runs 24 FMAs per wait (was 8), amortizes loop
// control 3x. Live growth ~18 VGPR (3 c3 + 3 xd) -- far from the promotion
// cliff (R2/R3/R4/R10: FULL unroll spills at 256 VGPR; axis closed).
// Accumulation order d-ascending preserved -> bitwise-identical f.
// 256 threads, 2 nodes/thread, x in LDS float2[i][tid], coeffs staged once
// to LDS, wave-uniform broadcast reads. Grid = NBLK, internal tile loop.
// ---------------------------------------------------------------------------
__global__ __launch_bounds__(256) void k_main(const float* __restrict__ x,
        const int* __restrict__ cnt, const int* __restrict__ list,
        const float* __restrict__ U3sym, const float* __restrict__ U2sym,
        const float* __restrict__ U1_0e, const float* __restrict__ U1_1o,
        const float* __restrict__ W3_0e, const float* __restrict__ W3_1o,
        const float* __restrict__ W2_0e, const float* __restrict__ W2_1o,
        const float* __restrict__ W1_0e, const float* __restrict__ W1_1o,
        float* __restrict__ fout) {
    __shared__ float  cfs[NMONO * 4];        // 3504 B
    __shared__ float2 xsh[9 * 256];          // 18432 B, [i][tid]
    int blk = blockIdx.x;                    // s*128 + c
    int s = blk >> 7, c = blk & 127;
    int n = cnt[s];
    if (n == 0) return;                      // block-uniform exit (before sync)

    int tid = threadIdx.x;

    // ---- coefficient preamble (fused k_coeff, unchanged math) ----
    for (int e = tid; e < NMONO * 4; e += 256) {
        int m = e >> 2, og = e & 3;
        float val;
        if (m < NCUB) {
            const float* W3 = (og == 0) ? W3_0e : W3_1o;   // [s][k][c] 512/128/1
            const float* u  = U3sym + (og * 165 + m) * 4;
            val = u[0] * W3[s*512 +       c] + u[1] * W3[s*512 + 128 + c]
                + u[2] * W3[s*512 + 256 + c] + u[3] * W3[s*512 + 384 + c];
        } else if (m < NCUB + NQUAD) {
            int q = m - NCUB;
            const float* W2 = (og == 0) ? W2_0e : W2_1o;   // [s][k][c] 256/128/1
            const float* u  = U2sym + (og * 45 + q) * 2;
            val = u[0] * W2[s*256 + c] + u[1] * W2[s*256 + 128 + c];
        } else {
            int l = m - (NCUB + NQUAD);
            const float* U1 = (og == 0) ? U1_0e : U1_1o;   // [o][i][k=1]
            const float* W1 = (og == 0) ? W1_0e : W1_1o;   // [s][1][c]
            int o = (og == 0) ? 0 : og - 1;
            val = U1[o * 9 + l] * W1[s * 128 + c];
        }
        cfs[e] = val;
    }

    const int* __restrict__ lst = list + s * N_NODES;
    const float4* __restrict__ cf4 = (const float4*)cfs;

    #define FMA8(cf, q0, q1) \
        a0[0] = fmaf(cf.x, q0, a0[0]);  a1[0] = fmaf(cf.x, q1, a1[0]); \
        a0[1] = fmaf(cf.y, q0, a0[1]);  a1[1] = fmaf(cf.y, q1, a1[1]); \
        a0[2] = fmaf(cf.z, q0, a0[2]);  a1[2] = fmaf(cf.z, q1, a1[2]); \
        a0[3] = fmaf(cf.w, q0, a0[3]);  a1[3] = fmaf(cf.w, q1, a1[3]);

    for (int base = 0; base < n; base += 512) {
        __syncthreads();                     // cfs ready / prior tile's xsh reads done
        int i0 = base + tid;
        int i1 = i0 + 256;
        int b0 = lst[i0 < n ? i0 : 0];
        int b1 = lst[i1 < n ? i1 : 0];
        const float* xp0 = x + ((size_t)b0 * C_CH + c) * 9;
        const float* xp1 = x + ((size_t)b1 * C_CH + c) * 9;
        #pragma unroll
        for (int i = 0; i < 9; i++)
            xsh[i * 256 + tid] = make_float2(xp0[i], xp1[i]);
        __syncthreads();

        float a0[4] = {0.f, 0.f, 0.f, 0.f};
        float a1[4] = {0.f, 0.f, 0.f, 0.f};
        int mcub = 0, mquad = 0;

        #pragma unroll 1
        for (int a = 0; a < 9; a++) {
            float2 xa = xsh[a * 256 + tid];
            {   // linear term
                float4 cl = cf4[210 + a];
                FMA8(cl, xa.x, xa.y)
            }
            #pragma unroll 1
            for (int b = a; b < 9; b++) {
                float2 xb = xsh[b * 256 + tid];
                float p0 = xa.x * xb.x, p1 = xa.y * xb.y;
                {
                    float4 cq = cf4[165 + mquad]; mquad++;
                    FMA8(cq, p0, p1)
                }
                // ---- d-loop, manually unrolled x3 (order preserved) ----
                int d = b;
                #pragma unroll 1
                for (; d + 3 <= 9; d += 3) {
                    float2 xd0 = xsh[ d      * 256 + tid];
                    float2 xd1 = xsh[(d + 1) * 256 + tid];
                    float2 xd2 = xsh[(d + 2) * 256 + tid];
                    float4 c30 = cf4[mcub];
                    float4 c31 = cf4[mcub + 1];
                    float4 c32 = cf4[mcub + 2];
                    mcub += 3;
                    float q00 = p0 * xd0.x, q01 = p1 * xd0.y;
                    float q10 = p0 * xd1.x, q11 = p1 * xd1.y;
                    float q20 = p0 * xd2.x, q21 = p1 * xd2.y;
                    FMA8(c30, q00, q01)
                    FMA8(c31, q10, q11)
                    FMA8(c32, q20, q21)
                }
                #pragma unroll 1
                for (; d < 9; d++) {
                    float2 xd = xsh[d * 256 + tid];
                    float4 c3 = cf4[mcub]; mcub++;
                    float q0 = p0 * xd.x, q1 = p1 * xd.y;
                    FMA8(c3, q0, q1)
                }
            }
        }
        if (i0 < n) *(float4*)&fout[((size_t)b0 * C_CH + c) * 4] = make_float4(a0[0], a0[1], a0[2], a0[3]);
        if (i1 < n) *(float4*)&fout[((size_t)b1 * C_CH + c) * 4] = make_float4(a1[0], a1[1], a1[2], a1[3]);
    }
    #undef FMA8
}

// ---------------------------------------------------------------------------
// Kernel 3: epilogue linear (round-0/5/6 version, unchanged).
// ---------------------------------------------------------------------------
__global__ __launch_bounds__(256) void k_epi(const float* __restrict__ f,
        const float* __restrict__ W0, const float* __restrict__ W1,
        const float* __restrict__ bias, float* __restrict__ out) {
    __shared__ float smem[128 * 65];        // ftile [c][n(64)+pad]; reused as trbuf [j][n]
    int bx = blockIdx.x;
    int ntile = bx >> 3, jg = bx & 7;       // 64 n-tiles x 8 j-groups of 64
    int n0 = ntile * 64;
    int t  = threadIdx.x;
    int o  = jg >> 1;                        // output component 0..3 (uniform per block)

    #pragma unroll
    for (int r = 0; r < 32; ++r) {
        int flat = r * 256 + t;              // 8192 = 64n * 128c
        int n = flat >> 7, c = flat & 127;
        smem[c * 65 + n] = f[(size_t)(n0 + n) * 512 + c * 4 + o];
    }
    __syncthreads();

    int w    = __builtin_amdgcn_readfirstlane((int)(t >> 6));
    int lane = t & 63;
    int mb   = (jg & 1) * 64 + w * 16;       // wave's m base (uniform)
    const float* __restrict__ Wsel = (o == 0) ? W0 : W1;

    float acc[16];
    #pragma unroll
    for (int jj = 0; jj < 16; jj++) acc[jj] = 0.f;

    #pragma unroll 4
    for (int c = 0; c < 128; ++c) {
        float fv = smem[c * 65 + lane];
        #pragma unroll
        for (int jj = 0; jj < 16; jj++)
            acc[jj] = fmaf(fv, Wsel[c * 128 + mb + jj], acc[jj]);
    }
    __syncthreads();                          // all waves done reading ftile

    const float scale = 0.08838834764831845f; // 1/sqrt(128)
    #pragma unroll
    for (int jj = 0; jj < 16; jj++) {
        float v = acc[jj] * scale;
        if (o == 0) v += bias[mb + jj];
        smem[(w * 16 + jj) * 65 + lane] = v;  // trbuf[j_local][n]
    }
    __syncthreads();

    #pragma unroll
    for (int r = 0; r < 16; ++r) {
        int flat = r * 256 + t;               // 4096 = 64j * 64n
        int jl = flat & 63, n = flat >> 6;
        int m  = (jg & 1) * 64 + jl;
        int col = (o == 0) ? m : (128 + m * 3 + (o - 1));
        out[(size_t)(n0 + n) * 512 + col] = smem[jl * 65 + n];
    }
}

extern "C" void kernel_launch(void* const* d_in, const int* in_sizes, int n_in,
                              void* d_out, int out_size, void* d_ws, size_t ws_size,
                              hipStream_t stream) {
    const float* x     = (const float*)d_in[0];
    const int*   spec  = (const int*)  d_in[1];
    const float* U3_0e = (const float*)d_in[2];
    const float* U2_0e = (const float*)d_in[3];
    const float* U1_0e = (const float*)d_in[4];
    const float* W3_0e = (const float*)d_in[5];
    const float* W2_0e = (const float*)d_in[6];
    const float* W1_0e = (const float*)d_in[7];
    const float* U3_1o = (const float*)d_in[8];
    const float* U2_1o = (const float*)d_in[9];
    const float* U1_1o = (const float*)d_in[10];
    const float* W3_1o = (const float*)d_in[11];
    const float* W2_1o = (const float*)d_in[12];
    const float* W1_1o = (const float*)d_in[13];
    const float* Wlin0 = (const float*)d_in[14];
    const float* Wlin1 = (const float*)d_in[15];
    const float* bias0 = (const float*)d_in[16];
    float* out = (float*)d_out;

    char* ws = (char*)d_ws;
    int*   cnt   = (int*)  (ws + WS_CNT);
    int*   list  = (int*)  (ws + WS_LIST);
    float* U3sym = (float*)(ws + WS_U3SYM);
    float* U2sym = (float*)(ws + WS_U2SYM);
    float* f     = (float*)(ws + WS_F);
    (void)in_sizes; (void)n_in; (void)out_size; (void)ws_size;

    // K1: blocks 0..7 = symmetrize U3/U2; block 8 = species bucketing.
    hipLaunchKernelGGL(k_prep, dim3(9), dim3(256), 0, stream,
                       U3_0e, U3_1o, U2_0e, U2_1o, spec, cnt, list, U3sym, U2sym);
    // K2: coeff-fused contraction, d-loop unrolled x3. Tile loop inside.
    hipLaunchKernelGGL(k_main, dim3(NBLK), dim3(256), 0, stream,
                       x, cnt, list, U3sym, U2sym, U1_0e, U1_1o,
                       W3_0e, W3_1o, W2_0e, W2_1o, W1_0e, W1_1o, f);
    // K3: epilogue linear.
    hipLaunchKernelGGL(k_epi, dim3(512), dim3(256), 0, stream,
                       f, Wlin0, Wlin1, bias0, out);
}